// Round 6
// baseline (2897.329 us; speedup 1.0000x reference)
//
#include <hip/hip_runtime.h>
#include <hip/hip_bf16.h>

typedef __bf16  bf16x8  __attribute__((ext_vector_type(8)));
typedef short   short8_t __attribute__((ext_vector_type(8)));
typedef float   float4_t __attribute__((ext_vector_type(4)));

#define MFMA(a, b, c) __builtin_amdgcn_mfma_f32_16x16x32_bf16((a), (b), (c), 0, 0, 0)

#define LOG2E      1.4426950408889634f
#define TWO_LOG2E  2.8853900817779268f

__device__ __forceinline__ unsigned short f2bf(float f) {
  unsigned u = __builtin_bit_cast(unsigned, f);
  unsigned r = ((u >> 16) & 1u) + 0x7FFFu;   // round-to-nearest-even
  return (unsigned short)((u + r) >> 16);
}
// x pre-scaled by LOG2E
__device__ __forceinline__ float sig2(float x) {
  return __builtin_amdgcn_rcpf(1.f + __builtin_amdgcn_exp2f(-x));
}
// x pre-scaled by 2*LOG2E
__device__ __forceinline__ float tanh2s(float x) {
  return 1.f - 2.f * __builtin_amdgcn_rcpf(1.f + __builtin_amdgcn_exp2f(x));
}

// 256 blocks x 512 threads (8 waves), 32 rows/block. Wave w owns hidden units
// [16w,16w+16). h1f double-buffered with STATIC addresses via 2x-unrolled t-loop.
// xf(t) aliases the first 2 KiB of the buffer BP(t) will write (dead h1(t-2)).
// Per step, 3 __syncthreads barriers:
//   BP(t):  store x(t) (drains behind MFMAs at B1); cell1(t) 64 MFMA
//           (reads h0f(t), RB=h1(t-1)) + cell0-h(t+1) 32 MFMA (shares the
//           same h0f(t) A-frags -> accN) + act1 -> write WB=h1(t)
//   B1      (publish h1(t); h0f(t)/RB reads done)
//   PROJ(t+1): w<4: reads WB=h1(t) + woutF -> xr=x(t+1); writes xf into RB corner
//   B2      (publish xf(t+1))
//   PX(t+1): x-part 8 MFMA (reads RB corner) + act0 m-interleaved -> h0f(t+1)
//   B3      (publish h0f(t+1))
__global__ __launch_bounds__(512, 2) void lstm_roll(
    const float* __restrict__ x0,  const float* __restrict__ W0,
    const float* __restrict__ b0v, const float* __restrict__ W1,
    const float* __restrict__ b1v, const float* __restrict__ Wout,
    const float* __restrict__ bout, const float* __restrict__ dts,
    const int* __restrict__ nsp,   float* __restrict__ out)
{
  __shared__ __align__(16) unsigned short w0h[8 * 4 * 4 * 512];  // 128 KiB W0 h-part B-frags [w][g][kt]
  __shared__ __align__(16) unsigned short woutF[2 * 4 * 512];    //   8 KiB Wout B-frags (dts*DT folded)
  __shared__ __align__(16) unsigned short h0f[4 * 2 * 512];      //   8 KiB h0 A-frags [kt][m]
  __shared__ __align__(16) unsigned short h1fA[4 * 2 * 512];     //   8 KiB h1 A-frags, buffer A
  __shared__ __align__(16) unsigned short h1fB[4 * 2 * 512];     //   8 KiB h1 A-frags, buffer B

  const int tid = threadIdx.x;
  const int w   = tid >> 6;
  const int l   = tid & 63;
  const int lm  = l & 15;
  const int lh  = l >> 4;
  const int T   = nsp[0];                 // 512 (even; loop is 2x-unrolled)
  const long rowStride = (long)(T + 1) * 32;
  const long bbase = (long)blockIdx.x * 32;

  // ---------------- weight gather / packing (once) ----------------
  bf16x8 w0x[4];       // W0 x-part B-frags (K=32)
  bf16x8 w1f[4][8];    // W1 B-frags (K=256; kt 0..3 h0-part, 4..7 h1-part)
  #pragma unroll
  for (int g = 0; g < 4; ++g) {
    const float sc = (g == 2) ? TWO_LOG2E : LOG2E;
    const int col = g * 128 + w * 16 + lm;
    {
      short8_t t8;
      #pragma unroll
      for (int e = 0; e < 8; ++e) t8[e] = (short)f2bf(sc * W0[(lh * 8 + e) * 512 + col]);
      w0x[g] = __builtin_bit_cast(bf16x8, t8);
    }
    #pragma unroll
    for (int kt = 0; kt < 8; ++kt) {
      short8_t t8;
      #pragma unroll
      for (int e = 0; e < 8; ++e) t8[e] = (short)f2bf(sc * W1[(kt * 32 + lh * 8 + e) * 512 + col]);
      w1f[g][kt] = __builtin_bit_cast(bf16x8, t8);
    }
    #pragma unroll
    for (int kt = 0; kt < 4; ++kt) {
      const int base = (((w * 4 + g) * 4) + kt) * 512 + l * 8;
      #pragma unroll
      for (int e = 0; e < 8; ++e)
        w0h[base + e] = f2bf(sc * W0[(32 + kt * 32 + lh * 8 + e) * 512 + col]);
    }
  }
  { // Wout B-frags with dts*DT folded in; 8 frags, one per wave
    const int n = w & 1, kt = w >> 1;
    if (kt < 4) {
      const float csc = dts[n * 16 + lm] * 0.01f;
      const int base = (n * 4 + kt) * 512 + l * 8;
      #pragma unroll
      for (int e = 0; e < 8; ++e)
        woutF[base + e] = f2bf(csc * Wout[(kt * 32 + lh * 8 + e) * 32 + (n * 16 + lm)]);
    }
  }
  float b0r[4], b1r[4];
  #pragma unroll
  for (int g = 0; g < 4; ++g) {
    const float sc = (g == 2) ? TWO_LOG2E : LOG2E;
    b0r[g] = sc * b0v[g * 128 + w * 16 + lm];
    b1r[g] = sc * b1v[g * 128 + w * 16 + lm];
  }

  // proj mapping: waves 0..3 own (m_c, n_c) output quadrant
  const int m_c = w & 1, n_c = (w >> 1) & 1;
  float boutr = 0.f, xr[4] = {0.f, 0.f, 0.f, 0.f};
  long obase0 = 0;
  int  xfbase = 0;
  if (w < 4) {
    boutr = bout[n_c * 16 + lm] * dts[n_c * 16 + lm] * 0.01f;
    const int kin = n_c * 16 + lm;
    xfbase = m_c * 512 + (lh * 4 + 16 * (kin >> 3)) * 8 + (kin & 7);
    obase0 = (bbase + m_c * 16 + lh * 4) * rowStride + (n_c * 16 + lm);
    #pragma unroll
    for (int r = 0; r < 4; ++r) {
      xr[r] = x0[(bbase + m_c * 16 + lh * 4 + r) * 32 + n_c * 16 + lm];
      h1fB[xfbase + r * 8] = f2bf(xr[r]);   // xf(0) in wb(0)=B corner
    }
  }
  for (int i = tid; i < 4 * 2 * 512; i += 512) h1fA[i] = 0;   // h1(-1) = 0

  // h-write scatter base (fragment layout; same for h0f/h1f)
  const int hwb = ((w >> 1) * 2) * 512 +
                  (lh * 4 + 16 * (2 * (w & 1) + ((lm >> 3) & 1))) * 8 + (lm & 7);

  float4_t c0[2], c1[2];
  #pragma unroll
  for (int m = 0; m < 2; ++m) {
    c0[m] = (float4_t){0.f, 0.f, 0.f, 0.f};
    c1[m] = (float4_t){0.f, 0.f, 0.f, 0.f};
  }

  float4_t accN[2][4];   // cell0 gates accumulator for the NEXT step

#define BP_PHASE(T_IDX, RB, WB) do {                                           \
    if (w < 4) {                                                               \
      const long ob = obase0 + (long)(T_IDX) * 32;                             \
      _Pragma("unroll")                                                        \
      for (int r = 0; r < 4; ++r) out[ob + r * rowStride] = xr[r];             \
    }                                                                          \
    _Pragma("unroll")                                                          \
    for (int g = 0; g < 4; ++g) {                                              \
      accN[0][g] = (float4_t){b0r[g], b0r[g], b0r[g], b0r[g]};                 \
      accN[1][g] = (float4_t){b0r[g], b0r[g], b0r[g], b0r[g]};                 \
    }                                                                          \
    float4_t am[4];                                                            \
    _Pragma("unroll")                                                          \
    for (int g = 0; g < 4; ++g) am[g] = (float4_t){b1r[g], b1r[g], b1r[g], b1r[g]}; \
    _Pragma("unroll")                                                          \
    for (int kt = 0; kt < 4; ++kt) {                                           \
      const bf16x8 a0 = *(const bf16x8*)&h0f[(kt * 2 + 0) * 512 + l * 8];      \
      const bf16x8 a1 = *(const bf16x8*)&h0f[(kt * 2 + 1) * 512 + l * 8];      \
      _Pragma("unroll")                                                        \
      for (int g = 0; g < 4; ++g) {                                            \
        const bf16x8 bw = *(const bf16x8*)&w0h[(((w * 4 + g) * 4) + kt) * 512 + l * 8]; \
        accN[0][g] = MFMA(a0, bw, accN[0][g]);                                 \
        accN[1][g] = MFMA(a1, bw, accN[1][g]);                                 \
        am[g]      = MFMA(a0, w1f[g][kt], am[g]);                              \
      }                                                                        \
    }                                                                          \
    _Pragma("unroll")                                                          \
    for (int kt = 0; kt < 4; ++kt) {                                           \
      const bf16x8 a = *(const bf16x8*)&(RB)[(kt * 2 + 0) * 512 + l * 8];      \
      _Pragma("unroll")                                                        \
      for (int g = 0; g < 4; ++g) am[g] = MFMA(a, w1f[g][kt + 4], am[g]);      \
    }                                                                          \
    _Pragma("unroll")                                                          \
    for (int r = 0; r < 4; ++r) {                                              \
      const float iv = sig2(am[0][r]);                                         \
      const float fv = sig2(am[1][r]);                                         \
      const float gv = tanh2s(am[2][r]);                                       \
      const float ov = sig2(am[3][r]);                                         \
      const float cc = fv * c1[0][r] + iv * gv;                                \
      c1[0][r] = cc;                                                           \
      (WB)[hwb + r * 8] = f2bf(ov * tanh2s(cc * TWO_LOG2E));                   \
    }                                                                          \
    _Pragma("unroll")                                                          \
    for (int g = 0; g < 4; ++g) am[g] = (float4_t){b1r[g], b1r[g], b1r[g], b1r[g]}; \
    _Pragma("unroll")                                                          \
    for (int kt = 0; kt < 4; ++kt) {                                           \
      const bf16x8 a1 = *(const bf16x8*)&h0f[(kt * 2 + 1) * 512 + l * 8];      \
      _Pragma("unroll")                                                        \
      for (int g = 0; g < 4; ++g) am[g] = MFMA(a1, w1f[g][kt], am[g]);         \
    }                                                                          \
    _Pragma("unroll")                                                          \
    for (int kt = 0; kt < 4; ++kt) {                                           \
      const bf16x8 a = *(const bf16x8*)&(RB)[(kt * 2 + 1) * 512 + l * 8];      \
      _Pragma("unroll")                                                        \
      for (int g = 0; g < 4; ++g) am[g] = MFMA(a, w1f[g][kt + 4], am[g]);      \
    }                                                                          \
    _Pragma("unroll")                                                          \
    for (int r = 0; r < 4; ++r) {                                              \
      const float iv = sig2(am[0][r]);                                         \
      const float fv = sig2(am[1][r]);                                         \
      const float gv = tanh2s(am[2][r]);                                       \
      const float ov = sig2(am[3][r]);                                         \
      const float cc = fv * c1[1][r] + iv * gv;                                \
      c1[1][r] = cc;                                                           \
      (WB)[hwb + 512 + r * 8] = f2bf(ov * tanh2s(cc * TWO_LOG2E));             \
    }                                                                          \
  } while (0)

#define PROJ_PHASE(HSRC, XDST) do {                                            \
    if (w < 4) {                                                               \
      float4_t dacc = (float4_t){boutr, boutr, boutr, boutr};                  \
      _Pragma("unroll")                                                        \
      for (int kt = 0; kt < 4; ++kt) {                                         \
        const bf16x8 a  = *(const bf16x8*)&(HSRC)[(kt * 2 + m_c) * 512 + l * 8]; \
        const bf16x8 bw = *(const bf16x8*)&woutF[(n_c * 4 + kt) * 512 + l * 8]; \
        dacc = MFMA(a, bw, dacc);                                              \
      }                                                                        \
      _Pragma("unroll")                                                        \
      for (int r = 0; r < 4; ++r) {                                            \
        xr[r] += dacc[r];                                                      \
        (XDST)[xfbase + r * 8] = f2bf(xr[r]);                                  \
      }                                                                        \
    }                                                                          \
  } while (0)

#define PX_PHASE(XSRC) do {                                                    \
    const bf16x8 ax0 = *(const bf16x8*)&(XSRC)[l * 8];                         \
    _Pragma("unroll")                                                          \
    for (int g = 0; g < 4; ++g) accN[0][g] = MFMA(ax0, w0x[g], accN[0][g]);    \
    const bf16x8 ax1 = *(const bf16x8*)&(XSRC)[512 + l * 8];                   \
    _Pragma("unroll")                                                          \
    for (int r = 0; r < 4; ++r) {                                              \
      const float iv = sig2(accN[0][0][r]);                                    \
      const float fv = sig2(accN[0][1][r]);                                    \
      const float gv = tanh2s(accN[0][2][r]);                                  \
      const float ov = sig2(accN[0][3][r]);                                    \
      const float cc = fv * c0[0][r] + iv * gv;                                \
      c0[0][r] = cc;                                                           \
      h0f[hwb + r * 8] = f2bf(ov * tanh2s(cc * TWO_LOG2E));                    \
    }                                                                          \
    _Pragma("unroll")                                                          \
    for (int g = 0; g < 4; ++g) accN[1][g] = MFMA(ax1, w0x[g], accN[1][g]);    \
    _Pragma("unroll")                                                          \
    for (int r = 0; r < 4; ++r) {                                              \
      const float iv = sig2(accN[1][0][r]);                                    \
      const float fv = sig2(accN[1][1][r]);                                    \
      const float gv = tanh2s(accN[1][2][r]);                                  \
      const float ov = sig2(accN[1][3][r]);                                    \
      const float cc = fv * c0[1][r] + iv * gv;                                \
      c0[1][r] = cc;                                                           \
      h0f[hwb + 512 + r * 8] = f2bf(ov * tanh2s(cc * TWO_LOG2E));              \
    }                                                                          \
  } while (0)

  // prologue: accN(0) = bias (h0(-1)=0 so no h-part); h0(0) from x(0) only
  #pragma unroll
  for (int g = 0; g < 4; ++g) {
    accN[0][g] = (float4_t){b0r[g], b0r[g], b0r[g], b0r[g]};
    accN[1][g] = (float4_t){b0r[g], b0r[g], b0r[g], b0r[g]};
  }
  __syncthreads();          // publish packing, xf(0), h1fA zeros
  PX_PHASE(h1fB);           // act0(0) -> h0f(0)
  __syncthreads();

  #pragma unroll 1
  for (int t = 0; t < T; t += 2) {
    BP_PHASE(t, h1fA, h1fB);       __syncthreads();
    PROJ_PHASE(h1fB, h1fA);        __syncthreads();
    PX_PHASE(h1fA);                __syncthreads();
    BP_PHASE(t + 1, h1fB, h1fA);   __syncthreads();
    PROJ_PHASE(h1fA, h1fB);        __syncthreads();
    PX_PHASE(h1fB);                __syncthreads();
  }

  // epilogue: x(T) already in xr (computed by in-loop PROJ of t+1==T)
  if (w < 4) {
    const long ob = obase0 + (long)T * 32;
    #pragma unroll
    for (int r = 0; r < 4; ++r) out[ob + r * rowStride] = xr[r];
  }
}

extern "C" void kernel_launch(void* const* d_in, const int* in_sizes, int n_in,
                              void* d_out, int out_size, void* d_ws, size_t ws_size,
                              hipStream_t stream) {
  (void)n_in; (void)out_size; (void)d_ws; (void)ws_size;
  const float* x0   = (const float*)d_in[0];
  const float* W0   = (const float*)d_in[1];
  const float* b0   = (const float*)d_in[2];
  const float* W1   = (const float*)d_in[3];
  const float* b1   = (const float*)d_in[4];
  const float* Wout = (const float*)d_in[5];
  const float* bout = (const float*)d_in[6];
  const float* dts  = (const float*)d_in[7];
  const int*   nsp  = (const int*)d_in[8];
  float* out = (float*)d_out;

  const int B    = in_sizes[0] / 32;   // 8192
  const int grid = B / 32;             // 256 blocks, 32 batch rows each
  lstm_roll<<<dim3(grid), dim3(512), 0, stream>>>(x0, W0, b0, W1, b1, Wout, bout, dts, nsp, out);
}